// Round 1
// baseline (586.516 us; speedup 1.0000x reference)
//
#include <hip/hip_runtime.h>

#define BB   16
#define CC   32
#define HH   384
#define WW   384
#define HW   (HH * WW)        // 147456
#define HID  128
#define KOUT 288              // NK*K*K = 32*9
#define NPLANE (BB * CC)      // 512

// conv geometry: each thread = 4 cols (one float4) x 16 rows
#define CG_PER_ROW 96                         // 384/4 col-groups
#define ROWS_PER_THREAD 16
#define NBANDS (HH / ROWS_PER_THREAD)         // 24
#define THREADS_PER_PLANE (CG_PER_ROW * NBANDS)   // 2304
#define BLOCKS_PER_PLANE (THREADS_PER_PLANE / 256) // 9

typedef float f4 __attribute__((ext_vector_type(4)));

// ---------------------------------------------------------------------------
// 1) Global average pool: one block per (b,c) plane, 1024 threads
//    (32 waves/CU for full latency hiding on the stream). float4 loads.
// ---------------------------------------------------------------------------
__global__ __launch_bounds__(1024) void pool_kernel(const float* __restrict__ x,
                                                    float* __restrict__ pooled) {
    const int bc = blockIdx.x;
    const f4* pv = (const f4*)(x + (size_t)bc * HW);
    float s = 0.f;
    for (int i = threadIdx.x; i < HW / 4; i += 1024) {
        f4 v = pv[i];
        s += (v.x + v.y) + (v.z + v.w);
    }
#pragma unroll
    for (int off = 32; off; off >>= 1) s += __shfl_down(s, off);
    __shared__ float red[16];
    if ((threadIdx.x & 63) == 0) red[threadIdx.x >> 6] = s;
    __syncthreads();
    if (threadIdx.x == 0) {
        float t = 0.f;
#pragma unroll
        for (int wv = 0; wv < 16; ++wv) t += red[wv];
        pooled[bc] = t * (1.0f / (float)HW);
    }
}

// ---------------------------------------------------------------------------
// 2) MLP kernel generator: one block per batch sample. fp32. (unchanged —
//    a few µs, not worth touching until counters say otherwise)
// ---------------------------------------------------------------------------
__global__ __launch_bounds__(128) void mlp_kernel(const float* __restrict__ pooled,
                                                  const float* __restrict__ w1,
                                                  const float* __restrict__ b1,
                                                  const float* __restrict__ w2,
                                                  const float* __restrict__ b2,
                                                  float* __restrict__ kern) {
    const int b   = blockIdx.x;
    const int tid = threadIdx.x;
    __shared__ float pc[CC];
    __shared__ float hdn[HID];
    if (tid < CC) pc[tid] = pooled[b * CC + tid];
    __syncthreads();

    float a = b1[tid];
#pragma unroll
    for (int c = 0; c < CC; ++c) a += pc[c] * w1[c * HID + tid];
    hdn[tid] = fmaxf(a, 0.f);
    __syncthreads();

    for (int o = tid; o < KOUT; o += 128) {
        float a2 = b2[o];
#pragma unroll 8
        for (int j = 0; j < HID; ++j) a2 += hdn[j] * w2[j * KOUT + o];
        kern[b * KOUT + o] = a2;
    }
}

// ---------------------------------------------------------------------------
// 3) Depthwise 3x3 conv, zero padding — register sliding window, no LDS.
//    Thread owns a 4-wide float4 column strip for 16 consecutive rows.
//    Per output row: 1 float4 load + 2 predicated edge scalars (cache-hit),
//    36 FMA, 1 float4 nontemporal store. Vertical reuse lives in registers.
// ---------------------------------------------------------------------------
__device__ __forceinline__ void load_row6(const float* __restrict__ xp,
                                          int r, int c0, int cg, float* a) {
    if ((unsigned)r < (unsigned)HH) {
        const float* p = xp + r * WW + c0;
        const f4 v = *reinterpret_cast<const f4*>(p);
        a[0] = (cg > 0)              ? p[-1] : 0.f;   // left halo (L1 hit)
        a[1] = v.x; a[2] = v.y; a[3] = v.z; a[4] = v.w;
        a[5] = (cg < CG_PER_ROW - 1) ? p[4]  : 0.f;   // right halo (L1 hit)
    } else {
        a[0] = a[1] = a[2] = a[3] = a[4] = a[5] = 0.f;
    }
}

__global__ __launch_bounds__(256) void conv_kernel(const float* __restrict__ x,
                                                   const float* __restrict__ kern,
                                                   float* __restrict__ out) {
    // 9 blocks per plane (2304 threads) -> plane uniform per block
    const int plane = blockIdx.x / BLOCKS_PER_PLANE;
    const int rem   = (blockIdx.x % BLOCKS_PER_PLANE) * 256 + (int)threadIdx.x;
    const int band  = rem / CG_PER_ROW;
    const int cg    = rem - band * CG_PER_ROW;
    const int c0    = cg * 4;

    const float* xp = x   + (size_t)plane * HW;
    float*       op = out + (size_t)plane * HW;

    float w[9];
    const float* kw = kern + plane * 9;          // uniform -> scalar loads
#pragma unroll
    for (int t = 0; t < 9; ++t) w[t] = kw[t];

    const int r0 = band * ROWS_PER_THREAD;
    float aT[6], aM[6], aB[6];
    float aN[6] = {0.f, 0.f, 0.f, 0.f, 0.f, 0.f};
    load_row6(xp, r0 - 1, c0, cg, aT);
    load_row6(xp, r0,     c0, cg, aM);
    load_row6(xp, r0 + 1, c0, cg, aB);

#pragma unroll
    for (int i = 0; i < ROWS_PER_THREAD; ++i) {
        const int r = r0 + i;
        if (i < ROWS_PER_THREAD - 1)              // one-row lookahead prefetch
            load_row6(xp, r + 2, c0, cg, aN);

        f4 o;
        o.x = w[0]*aT[0] + w[1]*aT[1] + w[2]*aT[2]
            + w[3]*aM[0] + w[4]*aM[1] + w[5]*aM[2]
            + w[6]*aB[0] + w[7]*aB[1] + w[8]*aB[2];
        o.y = w[0]*aT[1] + w[1]*aT[2] + w[2]*aT[3]
            + w[3]*aM[1] + w[4]*aM[2] + w[5]*aM[3]
            + w[6]*aB[1] + w[7]*aB[2] + w[8]*aB[3];
        o.z = w[0]*aT[2] + w[1]*aT[3] + w[2]*aT[4]
            + w[3]*aM[2] + w[4]*aM[3] + w[5]*aM[4]
            + w[6]*aB[2] + w[7]*aB[3] + w[8]*aB[4];
        o.w = w[0]*aT[3] + w[1]*aT[4] + w[2]*aT[5]
            + w[3]*aM[3] + w[4]*aM[4] + w[5]*aM[5]
            + w[6]*aB[3] + w[7]*aB[4] + w[8]*aB[5];

        __builtin_nontemporal_store(o, reinterpret_cast<f4*>(op + (size_t)r * WW + c0));

#pragma unroll
        for (int t = 0; t < 6; ++t) { aT[t] = aM[t]; aM[t] = aB[t]; aB[t] = aN[t]; }
    }
}

// ---------------------------------------------------------------------------
extern "C" void kernel_launch(void* const* d_in, const int* in_sizes, int n_in,
                              void* d_out, int out_size, void* d_ws, size_t ws_size,
                              hipStream_t stream) {
    const float* x  = (const float*)d_in[0];
    const float* w1 = (const float*)d_in[1];
    const float* b1 = (const float*)d_in[2];
    const float* w2 = (const float*)d_in[3];
    const float* b2 = (const float*)d_in[4];
    float* out = (float*)d_out;

    float* pooled = (float*)d_ws;        // 512 floats
    float* kern   = pooled + BB * CC;    // 16*288 = 4608 floats

    pool_kernel<<<NPLANE, 1024, 0, stream>>>(x, pooled);
    mlp_kernel<<<BB, 128, 0, stream>>>(pooled, w1, b1, w2, b2, kern);
    conv_kernel<<<NPLANE * BLOCKS_PER_PLANE, 256, 0, stream>>>(x, kern, out);
}